// Round 10
// baseline (4308.125 us; speedup 1.0000x reference)
//
#include <hip/hip_runtime.h>
#include <cstdint>
#include <cstddef>

// ---------------- types ----------------
typedef _Float16 half8 __attribute__((ext_vector_type(8)));
typedef float floatx4 __attribute__((ext_vector_type(4)));

typedef __attribute__((address_space(3))) unsigned lds_u32;
typedef const __attribute__((address_space(1))) unsigned glb_u32;

#define BK 64   // two 32-k sub-tiles per LDS buffer (dbuf core)

__device__ __forceinline__ void glds16(const void* g, void* l) {
    // async global->LDS, 16B per lane; LDS dest = wave-uniform base + lane*16
    __builtin_amdgcn_global_load_lds((glb_u32*)g, (lds_u32*)l, 16, 0, 0);
}

template <int N>
__device__ __forceinline__ void waitv() {
    asm volatile("s_waitcnt vmcnt(%0)" :: "n"(N) : "memory");
}

__device__ __forceinline__ void barfence() {
    asm volatile("" ::: "memory");
    __builtin_amdgcn_s_barrier();
    asm volatile("" ::: "memory");
}

template <int N> struct IC { static constexpr int value = N; };

__device__ __forceinline__ float fast_tanh(float x) {
    float ax = fabsf(x);
    float e  = __expf(-2.0f * ax);
    float t  = (1.0f - e) / (1.0f + e);
    return x < 0.0f ? -t : t;
}

// ---------------- XCD-aware block mapping ----------------
template <int MT, int NT, int NPX>
__device__ __forceinline__ void map_block(int id, int& mt, int& nt) {
    constexpr int NG  = NT / NPX;   // n-groups
    constexpr int XPG = 8 / NG;     // XCDs per group
    const int xcd  = id & 7;
    const int slot = id >> 3;
    nt = (xcd % NG) * NPX + (slot % NPX);
    mt = (xcd / NG) * (MT / XPG) + slot / NPX;
}

// ---------------- G1/G2: 8-phase-style pipelined kernel (R10) -------------
// 256x128 tile, 8 waves (4m x 2n) of 64x64, 512 thr, 96 KB LDS, 1 blk/CU.
// K split into 32-k slices; 4 LDS slots; prefetch depth 3 slices.
// Phase(s) [m201 template order — reads BEFORE barrier, vmcnt confirms s+1]:
//   ds_read 8 x b128 (slice s, slot s&3)   <- s confirmed in phase s-1
//   glds 3 (slice s+3 -> slot (s-1)&3)     <- writable: s-1 reads retired
//   s_waitcnt vmcnt(6)                     <- slice s+1 landed; s+2,s+3 fly
//   barrier; lgkmcnt(0); setprio(1); 16 MFMA; setprio(0); barrier
// Steady-state vmcnt never 0 (T4); tail drains 3->0.
// Swizzle per 16-row x 32-k chunk: verified conflict-free (rounds 0-9).
template <bool WITH_T>
__global__ __launch_bounds__(512, 2)
void gemm_bias_tanh_p8(const _Float16* __restrict__ A, const _Float16* __restrict__ BT,
                       _Float16* __restrict__ out, const float* __restrict__ bias,
                       const float* __restrict__ brow, float t, int N, int K) {
    int mt, nt;
    map_block<16, 16, 4>(blockIdx.x, mt, nt);
    const unsigned bm0 = (unsigned)mt * 256;
    const unsigned bn0 = (unsigned)nt * 128;

    __shared__ __align__(16) _Float16 As[4][256 * 32];   // 64 KB
    __shared__ __align__(16) _Float16 Bs[4][128 * 32];   // 32 KB

    const int tid  = threadIdx.x;
    const int lane = tid & 63;
    const int wid  = tid >> 6;            // 0..7; wave grid 4 (m) x 2 (n)
    const int srow = lane >> 2;
    const int skq  = (lane & 3) ^ ((lane >> 3) & 3);
    const int quad = lane >> 4;
    const int l16  = lane & 15;
    const int wmc  = (wid >> 1) * 4;      // A chunk base (wave row * 64/16)
    const int wnc  = (wid & 1) * 4;       // B chunk base
    const int rdoff = l16 * 32 + ((quad ^ ((l16 >> 1) & 3)) << 3);

    const unsigned kstr = (unsigned)K * 2u;
    const unsigned aB0  = (bm0 + (unsigned)srow) * kstr + (unsigned)(skq * 16);
    const unsigned bB0  = (bn0 + (unsigned)srow) * kstr + (unsigned)(skq * 16);
    const char* Abase = (const char*)A;
    const char* Bbase = (const char*)BT;

    floatx4 acc[4][4];
#pragma unroll
    for (int i = 0; i < 4; ++i)
#pragma unroll
        for (int j = 0; j < 4; ++j)
            acc[i][j] = 0.0f;

    // stage one 32-k slice: 16 A-chunks + 8 B-chunks, 8 waves -> 3 glds/wave
    auto stageS = [&](int s) {
        const unsigned kb   = (unsigned)s * 64u;     // 32 k * 2 B
        const int      slot = s & 3;
        glds16(Abase + (aB0 + (unsigned)wid       * (16u * kstr) + kb),
               &As[slot][wid * 512]);
        glds16(Abase + (aB0 + (unsigned)(wid + 8) * (16u * kstr) + kb),
               &As[slot][(wid + 8) * 512]);
        glds16(Bbase + (bB0 + (unsigned)wid       * (16u * kstr) + kb),
               &Bs[slot][wid * 512]);
    };

    auto phase = [&](int s, auto dc) {
        constexpr int D = decltype(dc)::value;   // slices in flight beyond s
        const int slot = s & 3;
        half8 av[4], bv[4];
#pragma unroll
        for (int i = 0; i < 4; ++i)
            av[i] = *(const half8*)(&As[slot][(wmc + i) * 512 + rdoff]);
#pragma unroll
        for (int j = 0; j < 4; ++j)
            bv[j] = *(const half8*)(&Bs[slot][(wnc + j) * 512 + rdoff]);
        if constexpr (D == 3) stageS(s + 3);
        if constexpr (D >= 1) waitv<(D - 1) * 3>();  // confirm slice s+1
        barfence();
        asm volatile("s_waitcnt lgkmcnt(0)" ::: "memory");
        __builtin_amdgcn_s_setprio(1);
#pragma unroll
        for (int i = 0; i < 4; ++i)
#pragma unroll
            for (int j = 0; j < 4; ++j)
                acc[i][j] = __builtin_amdgcn_mfma_f32_16x16x32_f16(av[i], bv[j], acc[i][j], 0, 0, 0);
        __builtin_amdgcn_s_setprio(0);
        barfence();
    };

    // prologue: slices 0,1,2 staged; vmcnt(6) confirms slice 0; barrier
    stageS(0); stageS(1); stageS(2);
    waitv<6>();
    barfence();

    const int NP = K >> 5;               // 32-k slices (>= 4 for K>=128)
    int s = 0;
    for (; s + 3 < NP; ++s) phase(s, IC<3>{});
    phase(s, IC<2>{}); ++s;
    phase(s, IC<1>{}); ++s;
    phase(s, IC<0>{});

    // epilogue: per-wave 64x64; C/D layout col=lane&15, row=quad*4+reg
    const size_t m0 = bm0 + (size_t)(wid >> 1) * 64;
    const size_t n0 = bn0 + (size_t)(wid & 1) * 64;
#pragma unroll
    for (int j = 0; j < 4; ++j) {
        const size_t col = n0 + j * 16 + l16;
        float b = bias[col];
        if (WITH_T) b += t * brow[col];
#pragma unroll
        for (int i = 0; i < 4; ++i) {
            const size_t rbase = m0 + i * 16 + quad * 4;
#pragma unroll
            for (int r = 0; r < 4; ++r) {
                out[(rbase + r) * (size_t)N + col] = (_Float16)fast_tanh(acc[i][j][r] + b);
            }
        }
    }
}

// ---------------- dbuf GEMM core (R5-proven, kept for G3) -----------------
template <int TBM, int TBN, int MF, int NF, int NW>
__device__ __forceinline__ void gemm_acc_db(const _Float16* __restrict__ A,
                                            const _Float16* __restrict__ BT,
                                            unsigned m0, unsigned n0,
                                            int K, floatx4 acc[MF][NF]) {
    constexpr int CW = TBN / (16 * NF);
    constexpr int RW = TBM / (16 * MF);
    static_assert(RW * CW == NW, "wave grid must use all waves");
    constexpr int AH  = TBM * 32;
    constexpr int BH  = TBN * 32;
    constexpr int NCA = TBM / 16;
    constexpr int NCB = TBN / 16;
    constexpr int UA  = (NCA + NW - 1) / NW;
    constexpr int UB  = (NCB + NW - 1) / NW;

    __shared__ __align__(16) _Float16 As[2][TBM * BK];
    __shared__ __align__(16) _Float16 Bs[2][TBN * BK];

    const int tid  = threadIdx.x;
    const int lane = tid & 63;
    const int wid  = tid >> 6;

    const int srow = lane >> 2;
    const int skq  = (lane & 3) ^ ((lane >> 3) & 3);
    const int quad = lane >> 4;
    const int l16  = lane & 15;
    const int wm   = (wid / CW) * (16 * MF);
    const int wn   = (wid % CW) * (16 * NF);

    const unsigned kstr = (unsigned)K * 2u;
    const unsigned aB0  = (m0 + (unsigned)srow) * kstr + (unsigned)(skq * 16);
    const unsigned bB0  = (n0 + (unsigned)srow) * kstr + (unsigned)(skq * 16);
    const char* Abase = (const char*)A;
    const char* Bbase = (const char*)BT;

#pragma unroll
    for (int i = 0; i < MF; ++i)
#pragma unroll
        for (int j = 0; j < NF; ++j)
            acc[i][j] = 0.0f;

    auto stage = [&](int buf, unsigned kb) {
#pragma unroll
        for (int h = 0; h < 2; ++h) {
#pragma unroll
            for (int u = 0; u < UA; ++u) {
                const int c = wid + u * NW;
                if ((NCA % NW == 0) || c < NCA)
                    glds16(Abase + (aB0 + (unsigned)c * (16u * kstr) + kb + (unsigned)(h * 64)),
                           &As[buf][h * AH + c * 512]);
            }
#pragma unroll
            for (int u = 0; u < UB; ++u) {
                const int c = wid + u * NW;
                if ((NCB % NW == 0) || c < NCB)
                    glds16(Bbase + (bB0 + (unsigned)c * (16u * kstr) + kb + (unsigned)(h * 64)),
                           &Bs[buf][h * BH + c * 512]);
            }
        }
    };

    const int rdoff = l16 * 32 + ((quad ^ ((l16 >> 1) & 3)) << 3);
    const unsigned Kb = (unsigned)K * 2u;
    const unsigned BKb = BK * 2u;

    stage(0, 0);
    int cur = 0;
    for (unsigned kb = 0; kb < Kb; kb += BKb) {
        __syncthreads();
        if (kb + BKb < Kb) stage(cur ^ 1, kb + BKb);

#pragma unroll
        for (int h = 0; h < 2; ++h) {
            half8 av[MF], bv[NF];
#pragma unroll
            for (int i = 0; i < MF; ++i)
                av[i] = *(const half8*)(&As[cur][h * AH + ((wm >> 4) + i) * 512 + rdoff]);
#pragma unroll
            for (int j = 0; j < NF; ++j)
                bv[j] = *(const half8*)(&Bs[cur][h * BH + ((wn >> 4) + j) * 512 + rdoff]);
#pragma unroll
            for (int i = 0; i < MF; ++i)
#pragma unroll
                for (int j = 0; j < NF; ++j)
                    acc[i][j] = __builtin_amdgcn_mfma_f32_16x16x32_f16(av[i], bv[j], acc[i][j], 0, 0, 0);
        }
        cur ^= 1;
    }
}

// ---------------- GEMM3 (R9-verbatim): 64x128 dbuf + RK4, h16 + fp16 accb -
__global__ __launch_bounds__(512)
void gemm_k_stage(const _Float16* __restrict__ A, const _Float16* __restrict__ BT,
                  const float* __restrict__ bias, float* __restrict__ hstate,
                  const _Float16* __restrict__ h16r, _Float16* __restrict__ h16w,
                  _Float16* __restrict__ accb, _Float16* __restrict__ x,
                  int stage, float c, float dt6, int N, int K) {
    int mt, nt;
    map_block<64, 8, 2>(blockIdx.x, mt, nt);
    const unsigned bm0 = (unsigned)mt * 64;
    const unsigned bn0 = (unsigned)nt * 128;

    floatx4 acc[2][2];
    gemm_acc_db<64, 128, 2, 2, 8>(A, BT, bm0, bn0, K, acc);

    const int tid  = threadIdx.x;
    const int lane = tid & 63;
    const int wid  = tid >> 6;          // wave grid 2 (m) x 4 (n)
    const int quad = lane >> 4;
    const int l16  = lane & 15;
    const size_t m0 = bm0 + (size_t)(wid / 4) * 32;
    const size_t n0 = bn0 + (size_t)(wid % 4) * 32;

#pragma unroll
    for (int j = 0; j < 2; ++j) {
        const size_t col = n0 + j * 16 + l16;
        const float b = bias[col];
#pragma unroll
        for (int i = 0; i < 2; ++i) {
            const size_t rbase = m0 + i * 16 + quad * 4;
#pragma unroll
            for (int r = 0; r < 4; ++r) {
                const size_t idx = (rbase + r) * (size_t)N + col;
                const float k = acc[i][j][r] + b;
                if (stage == 0) {
                    accb[idx] = (_Float16)k;
                    x[idx] = (_Float16)((float)h16r[idx] + c * k);
                } else if (stage < 3) {
                    accb[idx] = (_Float16)((float)accb[idx] + 2.0f * k);
                    x[idx] = (_Float16)((float)h16r[idx] + c * k);
                } else {
                    const float hn = hstate[idx] + dt6 * ((float)accb[idx] + k);
                    hstate[idx] = hn;
                    h16w[idx] = (_Float16)hn;   // next step's GEMM1 input
                }
            }
        }
    }
}

// ---------------- setup kernels ----------------
__global__ __launch_bounds__(256)
void transposeW(const float* __restrict__ W, _Float16* __restrict__ WT,
                int K, int N) {
    __shared__ float tile[32][33];
    const int tx = threadIdx.x;          // 0..31
    const int ty = threadIdx.y;          // 0..7
    const int n0 = blockIdx.x * 32;
    const int k0 = blockIdx.y * 32;
#pragma unroll
    for (int r = ty; r < 32; r += 8)
        tile[r][tx] = W[(size_t)(k0 + r) * N + n0 + tx];
    __syncthreads();
#pragma unroll
    for (int r = ty; r < 32; r += 8)
        WT[(size_t)(n0 + r) * K + k0 + tx] = (_Float16)tile[tx][r];
}

__global__ void copy_row(const float* __restrict__ W1, float* __restrict__ w1row, int N) {
    const int n = blockIdx.x * 256 + threadIdx.x;
    if (n < N) w1row[n] = W1[(size_t)1024 * N + n];
}

__global__ void init_h(const float* __restrict__ h0, float* __restrict__ hstate,
                       _Float16* __restrict__ h16, int n) {
    const int i = blockIdx.x * 256 + threadIdx.x;
    if (i < n) {
        const float v = h0[i];
        hstate[i] = v;
        h16[i] = (_Float16)v;
    }
}

// ---------------- launch ----------------
extern "C" void kernel_launch(void* const* d_in, const int* in_sizes, int n_in,
                              void* d_out, int out_size, void* d_ws, size_t ws_size,
                              hipStream_t stream) {
    const int B = 4096, H = 1024, H2 = 2048;

    const float* h0 = (const float*)d_in[0];
    const float* W1 = (const float*)d_in[1];  // (1025, 2048)
    const float* b1 = (const float*)d_in[2];  // (2048,)
    const float* W2 = (const float*)d_in[3];  // (2048, 2048)
    const float* b2 = (const float*)d_in[4];  // (2048,)
    const float* W3 = (const float*)d_in[5];  // (2048, 1024)
    const float* b3 = (const float*)d_in[6];  // (1024,)

    float* hstate = (float*)d_out;            // B*H fp32 state, final answer

    char* ws = (char*)d_ws;
    _Float16* x    = (_Float16*)ws; ws += (size_t)B * H  * 2;  // stage-0..2 GEMM1 input
    _Float16* h16  = (_Float16*)ws; ws += (size_t)B * H  * 2;  // fp16 h mirror
    _Float16* a1   = (_Float16*)ws; ws += (size_t)B * H2 * 2;  // layer-1 act
    _Float16* a2   = (_Float16*)ws; ws += (size_t)B * H2 * 2;  // layer-2 act
    _Float16* accb = (_Float16*)ws; ws += (size_t)B * H  * 2;  // RK4 k-accum (fp16)
    _Float16* W1T  = (_Float16*)ws; ws += (size_t)H2 * H  * 2; // (2048,1024)
    _Float16* W2T  = (_Float16*)ws; ws += (size_t)H2 * H2 * 2; // (2048,2048)
    _Float16* W3T  = (_Float16*)ws; ws += (size_t)H  * H2 * 2; // (1024,2048)
    float*   w1row = (float*)ws;    ws += (size_t)H2 * 4;      // t-row of W1, fp32

    // weight conversion + transpose (runs every call; weights restored by harness)
    const dim3 tblk(32, 8);
    transposeW<<<dim3(H2 / 32, H  / 32), tblk, 0, stream>>>(W1, W1T, H,  H2);
    transposeW<<<dim3(H2 / 32, H2 / 32), tblk, 0, stream>>>(W2, W2T, H2, H2);
    transposeW<<<dim3(H  / 32, H2 / 32), tblk, 0, stream>>>(W3, W3T, H2, H);
    copy_row<<<dim3(H2 / 256), 256, 0, stream>>>(W1, w1row, H2);
    init_h<<<dim3((B * H + 255) / 256), 256, 0, stream>>>(h0, hstate, h16, B * H);

    const float dt  = 0.1f;
    const float dt2 = 0.05f;
    const float dt6 = dt / 6.0f;

    const dim3 blk(512);
    const int g12 = (B / 256) * (H2 / 128);   // 256 blocks, 1/CU, XCD-mapped
    const int g3  = (B / 64) * (H / 128);     // 512 blocks, 2/CU, XCD-mapped

    for (int s = 0; s < 10; ++s) {
        const float ti = (float)s * dt;

        // k1 = f(ti, h)  — GEMM1 reads the fp16 h mirror
        gemm_bias_tanh_p8<true ><<<g12, blk, 0, stream>>>(h16, W1T, a1, b1, w1row, ti,       H2, H);
        gemm_bias_tanh_p8<false><<<g12, blk, 0, stream>>>(a1,  W2T, a2, b2, nullptr, 0.f,    H2, H2);
        gemm_k_stage<<<g3, blk, 0, stream>>>(a2, W3T, b3, hstate, h16, h16, accb, x, 0, dt2, dt6, H, H2);

        // k2 = f(ti+dt/2, h + dt/2*k1)
        gemm_bias_tanh_p8<true ><<<g12, blk, 0, stream>>>(x,  W1T, a1, b1, w1row, ti + dt2, H2, H);
        gemm_bias_tanh_p8<false><<<g12, blk, 0, stream>>>(a1, W2T, a2, b2, nullptr, 0.f,    H2, H2);
        gemm_k_stage<<<g3, blk, 0, stream>>>(a2, W3T, b3, hstate, h16, h16, accb, x, 1, dt2, dt6, H, H2);

        // k3 = f(ti+dt/2, h + dt/2*k2)
        gemm_bias_tanh_p8<true ><<<g12, blk, 0, stream>>>(x,  W1T, a1, b1, w1row, ti + dt2, H2, H);
        gemm_bias_tanh_p8<false><<<g12, blk, 0, stream>>>(a1, W2T, a2, b2, nullptr, 0.f,    H2, H2);
        gemm_k_stage<<<g3, blk, 0, stream>>>(a2, W3T, b3, hstate, h16, h16, accb, x, 2, dt,  dt6, H, H2);

        // k4 = f(ti+dt, h + dt*k3); h += dt/6*(k1+2k2+2k3+k4); h16 = fp16(h)
        gemm_bias_tanh_p8<true ><<<g12, blk, 0, stream>>>(x,  W1T, a1, b1, w1row, ti + dt,  H2, H);
        gemm_bias_tanh_p8<false><<<g12, blk, 0, stream>>>(a1, W2T, a2, b2, nullptr, 0.f,    H2, H2);
        gemm_k_stage<<<g3, blk, 0, stream>>>(a2, W3T, b3, hstate, h16, h16, accb, x, 3, dt,  dt6, H, H2);
    }
}

// Round 11
// 4073.449 us; speedup vs baseline: 1.0576x; 1.0576x over previous
//
#include <hip/hip_runtime.h>
#include <cstdint>
#include <cstddef>

// ---------------- types ----------------
typedef _Float16 half8 __attribute__((ext_vector_type(8)));
typedef float floatx4 __attribute__((ext_vector_type(4)));

typedef __attribute__((address_space(3))) unsigned lds_u32;
typedef const __attribute__((address_space(1))) unsigned glb_u32;

#define BK 64   // two 32-k sub-tiles per LDS buffer

__device__ __forceinline__ void glds16(const void* g, void* l) {
    // async global->LDS, 16B per lane; LDS dest = wave-uniform base + lane*16
    __builtin_amdgcn_global_load_lds((glb_u32*)g, (lds_u32*)l, 16, 0, 0);
}

__device__ __forceinline__ float fast_tanh(float x) {
    float ax = fabsf(x);
    float e  = __expf(-2.0f * ax);
    float t  = (1.0f - e) / (1.0f + e);
    return x < 0.0f ? -t : t;
}

// ---------------- XCD-aware block mapping ----------------
// R11: NPX chosen so each XCD's concurrent tile set is ~square (mt_span +
// nt_span panels minimized -> smallest L2 working set).
template <int MT, int NT, int NPX>
__device__ __forceinline__ void map_block(int id, int& mt, int& nt) {
    constexpr int NG  = NT / NPX;   // n-groups
    constexpr int XPG = 8 / NG;     // XCDs per group
    const int xcd  = id & 7;
    const int slot = id >> 3;
    nt = (xcd % NG) * NPX + (slot % NPX);
    mt = (xcd / NG) * (MT / XPG) + slot / NPX;
}

// ---------------- GEMM core (R5-proven skeleton + u32 addressing) ---------
// C[TBM x TBN] = A[TBM x K] * BT[TBN x K]^T, both fp16 row-major (BT = B^T).
// Per 16-row x 32-k chunk (512 elems): staging lane j (row j>>2) fetches
// 16B k-chunk kq = (j&3) ^ ((j>>3)&3) of the row's 64B -> LDS unit j.
// Fragment read: lane (quad,l16) reads unit l16*4 + (quad ^ ((l16>>1)&3)):
// conflict-free (SQ_LDS_BANK_CONFLICT = 0 across rounds 0-10).
// SESSION LEDGER (final):
//  - 1-block/CU configs: ALWAYS ~64 us on G2 (4 structures incl. faithful
//    8-phase counted-vmcnt port, R10). 2 barrier groups/CU dbuf = 46.5 us.
//  - R8: half-size N-tile doubled FETCH (41->74 MB) -> tile 128x128 fixed.
//  - Structure frozen at this skeleton; remaining levers are traffic only.
template <int TBM, int TBN, int MF, int NF, int NW>
__device__ __forceinline__ void gemm_acc_db(const _Float16* __restrict__ A,
                                            const _Float16* __restrict__ BT,
                                            unsigned m0, unsigned n0,
                                            int K, floatx4 acc[MF][NF]) {
    constexpr int CW = TBN / (16 * NF);   // waves along n
    constexpr int RW = TBM / (16 * MF);   // waves along m
    static_assert(RW * CW == NW, "wave grid must use all waves");
    constexpr int AH  = TBM * 32;         // elems per 32-k half of A tile
    constexpr int BH  = TBN * 32;
    constexpr int NCA = TBM / 16;         // 16-row staging chunks in A
    constexpr int NCB = TBN / 16;
    constexpr int UA  = (NCA + NW - 1) / NW;
    constexpr int UB  = (NCB + NW - 1) / NW;

    __shared__ __align__(16) _Float16 As[2][TBM * BK];
    __shared__ __align__(16) _Float16 Bs[2][TBN * BK];

    const int tid  = threadIdx.x;
    const int lane = tid & 63;
    const int wid  = tid >> 6;

    const int srow = lane >> 2;                     // row within 16-row chunk
    const int skq  = (lane & 3) ^ ((lane >> 3) & 3);// swizzled 16B k-chunk
    const int quad = lane >> 4;
    const int l16  = lane & 15;
    const int wm   = (wid / CW) * (16 * MF);
    const int wn   = (wid % CW) * (16 * NF);

    const unsigned kstr = (unsigned)K * 2u;         // row stride in bytes
    const unsigned aB0  = (m0 + (unsigned)srow) * kstr + (unsigned)(skq * 16);
    const unsigned bB0  = (n0 + (unsigned)srow) * kstr + (unsigned)(skq * 16);
    const char* Abase = (const char*)A;
    const char* Bbase = (const char*)BT;

#pragma unroll
    for (int i = 0; i < MF; ++i)
#pragma unroll
        for (int j = 0; j < NF; ++j)
            acc[i][j] = 0.0f;

    auto stage = [&](int buf, unsigned kb) {        // kb = byte offset of k0
#pragma unroll
        for (int h = 0; h < 2; ++h) {
#pragma unroll
            for (int u = 0; u < UA; ++u) {
                const int c = wid + u * NW;
                if ((NCA % NW == 0) || c < NCA)
                    glds16(Abase + (aB0 + (unsigned)c * (16u * kstr) + kb + (unsigned)(h * 64)),
                           &As[buf][h * AH + c * 512]);
            }
#pragma unroll
            for (int u = 0; u < UB; ++u) {
                const int c = wid + u * NW;
                if ((NCB % NW == 0) || c < NCB)
                    glds16(Bbase + (bB0 + (unsigned)c * (16u * kstr) + kb + (unsigned)(h * 64)),
                           &Bs[buf][h * BH + c * 512]);
            }
        }
    };

    const int rdoff = l16 * 32 + ((quad ^ ((l16 >> 1) & 3)) << 3);
    const unsigned Kb = (unsigned)K * 2u;           // total k bytes
    const unsigned BKb = BK * 2u;

    stage(0, 0);
    int cur = 0;
    for (unsigned kb = 0; kb < Kb; kb += BKb) {
        __syncthreads();                             // buf[cur] ready (vmcnt drain)
        if (kb + BKb < Kb) stage(cur ^ 1, kb + BKb); // overlap with MFMAs below

#pragma unroll
        for (int h = 0; h < 2; ++h) {
            half8 av[MF], bv[NF];
#pragma unroll
            for (int i = 0; i < MF; ++i)
                av[i] = *(const half8*)(&As[cur][h * AH + ((wm >> 4) + i) * 512 + rdoff]);
#pragma unroll
            for (int j = 0; j < NF; ++j)
                bv[j] = *(const half8*)(&Bs[cur][h * BH + ((wn >> 4) + j) * 512 + rdoff]);
#pragma unroll
            for (int i = 0; i < MF; ++i)
#pragma unroll
                for (int j = 0; j < NF; ++j)
                    acc[i][j] = __builtin_amdgcn_mfma_f32_16x16x32_f16(av[i], bv[j], acc[i][j], 0, 0, 0);
        }
        cur ^= 1;
    }
}

// C/D layout (verified m89/m91): col = lane&15, row = quad*4 + reg.

// ---------------- GEMM1/2: 128x128 tile, 8 waves of 64x32 (R7-proven) -----
// R11: map_block NPX 4 -> 8 (per-XCD 8x8 tile set, L2 ws 10 -> 8 MB).
template <bool WITH_T, int MT, int NT>
__global__ __launch_bounds__(512)
void gemm_bias_tanh(const _Float16* __restrict__ A, const _Float16* __restrict__ BT,
                    _Float16* __restrict__ out, const float* __restrict__ bias,
                    const float* __restrict__ brow, float t, int N, int K) {
    int mt, nt;
    map_block<MT, NT, 8>(blockIdx.x, mt, nt);
    const unsigned bm0 = (unsigned)mt * 128;
    const unsigned bn0 = (unsigned)nt * 128;

    floatx4 acc[4][2];
    gemm_acc_db<128, 128, 4, 2, 8>(A, BT, bm0, bn0, K, acc);

    const int tid  = threadIdx.x;
    const int lane = tid & 63;
    const int wid  = tid >> 6;          // 0..7; wave grid 2 (m) x 4 (n)
    const int quad = lane >> 4;
    const int l16  = lane & 15;
    const size_t m0 = bm0 + (size_t)(wid / 4) * 64;
    const size_t n0 = bn0 + (size_t)(wid % 4) * 32;

#pragma unroll
    for (int j = 0; j < 2; ++j) {
        const size_t col = n0 + j * 16 + l16;
        float b = bias[col];
        if (WITH_T) b += t * brow[col];
#pragma unroll
        for (int i = 0; i < 4; ++i) {
            const size_t rbase = m0 + i * 16 + quad * 4;
#pragma unroll
            for (int r = 0; r < 4; ++r) {
                out[(rbase + r) * (size_t)N + col] = (_Float16)fast_tanh(acc[i][j][r] + b);
            }
        }
    }
}

// ---------------- GEMM3 (R9 config) + RK4 stage, fp16 accb + h16 mirror ---
// 64x128 tile, 512 blocks, 2 blocks/CU, 16 waves/CU (proven).
// R11: map_block NPX 2 -> 8 (per-XCD 8 mt x 8 nt, L2 ws 9 -> 6 MB).
// Stages 0-2 read fp16 h16 (8 MB) instead of fp32 hstate (16 MB); stage 3
// keeps exact fp32 carry in hstate and refreshes h16 (= next GEMM1 input).
__global__ __launch_bounds__(512)
void gemm_k_stage(const _Float16* __restrict__ A, const _Float16* __restrict__ BT,
                  const float* __restrict__ bias, float* __restrict__ hstate,
                  const _Float16* __restrict__ h16r, _Float16* __restrict__ h16w,
                  _Float16* __restrict__ accb, _Float16* __restrict__ x,
                  int stage, float c, float dt6, int N, int K) {
    int mt, nt;
    map_block<64, 8, 8>(blockIdx.x, mt, nt);
    const unsigned bm0 = (unsigned)mt * 64;
    const unsigned bn0 = (unsigned)nt * 128;

    floatx4 acc[2][2];
    gemm_acc_db<64, 128, 2, 2, 8>(A, BT, bm0, bn0, K, acc);

    const int tid  = threadIdx.x;
    const int lane = tid & 63;
    const int wid  = tid >> 6;          // wave grid 2 (m) x 4 (n)
    const int quad = lane >> 4;
    const int l16  = lane & 15;
    const size_t m0 = bm0 + (size_t)(wid / 4) * 32;
    const size_t n0 = bn0 + (size_t)(wid % 4) * 32;

#pragma unroll
    for (int j = 0; j < 2; ++j) {
        const size_t col = n0 + j * 16 + l16;
        const float b = bias[col];
#pragma unroll
        for (int i = 0; i < 2; ++i) {
            const size_t rbase = m0 + i * 16 + quad * 4;
#pragma unroll
            for (int r = 0; r < 4; ++r) {
                const size_t idx = (rbase + r) * (size_t)N + col;
                const float k = acc[i][j][r] + b;
                if (stage == 0) {
                    accb[idx] = (_Float16)k;
                    x[idx] = (_Float16)((float)h16r[idx] + c * k);
                } else if (stage < 3) {
                    accb[idx] = (_Float16)((float)accb[idx] + 2.0f * k);
                    x[idx] = (_Float16)((float)h16r[idx] + c * k);
                } else {
                    const float hn = hstate[idx] + dt6 * ((float)accb[idx] + k);
                    hstate[idx] = hn;
                    h16w[idx] = (_Float16)hn;   // next step's GEMM1 input
                }
            }
        }
    }
}

// ---------------- setup kernels ----------------
__global__ __launch_bounds__(256)
void transposeW(const float* __restrict__ W, _Float16* __restrict__ WT,
                int K, int N) {
    __shared__ float tile[32][33];
    const int tx = threadIdx.x;          // 0..31
    const int ty = threadIdx.y;          // 0..7
    const int n0 = blockIdx.x * 32;
    const int k0 = blockIdx.y * 32;
#pragma unroll
    for (int r = ty; r < 32; r += 8)
        tile[r][tx] = W[(size_t)(k0 + r) * N + n0 + tx];
    __syncthreads();
#pragma unroll
    for (int r = ty; r < 32; r += 8)
        WT[(size_t)(n0 + r) * K + k0 + tx] = (_Float16)tile[tx][r];
}

__global__ void copy_row(const float* __restrict__ W1, float* __restrict__ w1row, int N) {
    const int n = blockIdx.x * 256 + threadIdx.x;
    if (n < N) w1row[n] = W1[(size_t)1024 * N + n];
}

__global__ void init_h(const float* __restrict__ h0, float* __restrict__ hstate,
                       _Float16* __restrict__ h16, int n) {
    const int i = blockIdx.x * 256 + threadIdx.x;
    if (i < n) {
        const float v = h0[i];
        hstate[i] = v;
        h16[i] = (_Float16)v;
    }
}

// ---------------- launch ----------------
extern "C" void kernel_launch(void* const* d_in, const int* in_sizes, int n_in,
                              void* d_out, int out_size, void* d_ws, size_t ws_size,
                              hipStream_t stream) {
    const int B = 4096, H = 1024, H2 = 2048;

    const float* h0 = (const float*)d_in[0];
    const float* W1 = (const float*)d_in[1];  // (1025, 2048)
    const float* b1 = (const float*)d_in[2];  // (2048,)
    const float* W2 = (const float*)d_in[3];  // (2048, 2048)
    const float* b2 = (const float*)d_in[4];  // (2048,)
    const float* W3 = (const float*)d_in[5];  // (2048, 1024)
    const float* b3 = (const float*)d_in[6];  // (1024,)

    float* hstate = (float*)d_out;            // B*H fp32 state, final answer

    char* ws = (char*)d_ws;
    _Float16* x    = (_Float16*)ws; ws += (size_t)B * H  * 2;  // stage-0..2 GEMM1 input
    _Float16* h16  = (_Float16*)ws; ws += (size_t)B * H  * 2;  // fp16 h mirror
    _Float16* a1   = (_Float16*)ws; ws += (size_t)B * H2 * 2;  // layer-1 act
    _Float16* a2   = (_Float16*)ws; ws += (size_t)B * H2 * 2;  // layer-2 act
    _Float16* accb = (_Float16*)ws; ws += (size_t)B * H  * 2;  // RK4 k-accum (fp16)
    _Float16* W1T  = (_Float16*)ws; ws += (size_t)H2 * H  * 2; // (2048,1024)
    _Float16* W2T  = (_Float16*)ws; ws += (size_t)H2 * H2 * 2; // (2048,2048)
    _Float16* W3T  = (_Float16*)ws; ws += (size_t)H  * H2 * 2; // (1024,2048)
    float*   w1row = (float*)ws;    ws += (size_t)H2 * 4;      // t-row of W1, fp32

    // weight conversion + transpose (runs every call; weights restored by harness)
    const dim3 tblk(32, 8);
    transposeW<<<dim3(H2 / 32, H  / 32), tblk, 0, stream>>>(W1, W1T, H,  H2);
    transposeW<<<dim3(H2 / 32, H2 / 32), tblk, 0, stream>>>(W2, W2T, H2, H2);
    transposeW<<<dim3(H  / 32, H2 / 32), tblk, 0, stream>>>(W3, W3T, H2, H);
    copy_row<<<dim3(H2 / 256), 256, 0, stream>>>(W1, w1row, H2);
    init_h<<<dim3((B * H + 255) / 256), 256, 0, stream>>>(h0, hstate, h16, B * H);

    const float dt  = 0.1f;
    const float dt2 = 0.05f;
    const float dt6 = dt / 6.0f;

    const dim3 blk(512);
    const int g12 = (B / 128) * (H2 / 128);   // 512 blocks, 2/CU, XCD-mapped
    const int g3  = (B / 64) * (H / 128);     // 512 blocks, 2/CU, XCD-mapped

    for (int s = 0; s < 10; ++s) {
        const float ti = (float)s * dt;

        // k1 = f(ti, h)  — GEMM1 reads the fp16 h mirror
        gemm_bias_tanh<true , 32, 16><<<g12, blk, 0, stream>>>(h16, W1T, a1, b1, w1row, ti,       H2, H);
        gemm_bias_tanh<false, 32, 16><<<g12, blk, 0, stream>>>(a1,  W2T, a2, b2, nullptr, 0.f,    H2, H2);
        gemm_k_stage<<<g3, blk, 0, stream>>>(a2, W3T, b3, hstate, h16, h16, accb, x, 0, dt2, dt6, H, H2);

        // k2 = f(ti+dt/2, h + dt/2*k1)
        gemm_bias_tanh<true , 32, 16><<<g12, blk, 0, stream>>>(x,  W1T, a1, b1, w1row, ti + dt2, H2, H);
        gemm_bias_tanh<false, 32, 16><<<g12, blk, 0, stream>>>(a1, W2T, a2, b2, nullptr, 0.f,    H2, H2);
        gemm_k_stage<<<g3, blk, 0, stream>>>(a2, W3T, b3, hstate, h16, h16, accb, x, 1, dt2, dt6, H, H2);

        // k3 = f(ti+dt/2, h + dt/2*k2)
        gemm_bias_tanh<true , 32, 16><<<g12, blk, 0, stream>>>(x,  W1T, a1, b1, w1row, ti + dt2, H2, H);
        gemm_bias_tanh<false, 32, 16><<<g12, blk, 0, stream>>>(a1, W2T, a2, b2, nullptr, 0.f,    H2, H2);
        gemm_k_stage<<<g3, blk, 0, stream>>>(a2, W3T, b3, hstate, h16, h16, accb, x, 2, dt,  dt6, H, H2);

        // k4 = f(ti+dt, h + dt*k3); h += dt/6*(k1+2k2+2k3+k4); h16 = fp16(h)
        gemm_bias_tanh<true , 32, 16><<<g12, blk, 0, stream>>>(x,  W1T, a1, b1, w1row, ti + dt,  H2, H);
        gemm_bias_tanh<false, 32, 16><<<g12, blk, 0, stream>>>(a1, W2T, a2, b2, nullptr, 0.f,    H2, H2);
        gemm_k_stage<<<g3, blk, 0, stream>>>(a2, W3T, b3, hstate, h16, h16, accb, x, 3, dt,  dt6, H, H2);
    }
}